// Round 3
// baseline (25352.789 us; speedup 1.0000x reference)
//
#include <hip/hip_runtime.h>
#include <hip/hip_bf16.h>
#include <math.h>

// Dims (fixed by the problem)
#define B_  16
#define S_  512
#define D_  768
#define H_  12
#define DN_ 64
#define F_  3072
#define L_  6
#define T_  (B_*S_)          // 8192 tokens

// ---------------------------------------------------------------------------
// Probe: is x int64 (stride 2) or int32 (stride 1)?  int64 little-endian with
// values in [0, 32000) has every odd 32-bit word == 0.
// ---------------------------------------------------------------------------
__global__ __launch_bounds__(64) void probe_x(const int* __restrict__ x,
                                              int* __restrict__ xstride) {
  if (threadIdx.x == 0) {
    int allzero = 1;
    for (int i = 0; i < 64; ++i) allzero &= (x[2 * i + 1] == 0) ? 1 : 0;
    *xstride = allzero ? 2 : 1;
  }
}

// ---------------------------------------------------------------------------
// Embedding lookup + sinusoidal positional encoding (computed on the fly)
// pe[s,c] = c even: sin(s*10000^(-c/768)); c odd: cos(s*10000^(-(c+1)/768))
// ---------------------------------------------------------------------------
__global__ __launch_bounds__(256) void embed_pe(const int* __restrict__ x,
                                                const int* __restrict__ xstride,
                                                const float* __restrict__ emb,
                                                float* __restrict__ h) {
  const int t = blockIdx.x;            // token index
  const int s = t & (S_ - 1);          // position within sequence
  const int tok = x[t * (*xstride)];
  const float* ep = emb + (size_t)tok * D_;
  const float pos = (float)s;
  for (int d = threadIdx.x; d < D_; d += 256) {
    float pe;
    if ((d & 1) == 0) {
      float freq = powf(10000.0f, -(float)d * (1.0f / 768.0f));
      pe = sinf(pos * freq);
    } else {
      float freq = powf(10000.0f, -(float)(d + 1) * (1.0f / 768.0f));
      pe = cosf(pos * freq);
    }
    h[(size_t)t * D_ + d] = ep[d] + pe;
  }
}

// ---------------------------------------------------------------------------
// C[M,N] = A[M,K] @ W + bias (all fp32), optional ReLU. 64x64 tile, BK=16,
// 256 threads, 4x4 micro-tile per thread.
// PERHEAD=1: W is [H, K, 64] per-head stacked (Wq/Wk/Wv layout); a 64-wide
// column block bn lies in head (bn>>6), contiguous [K,64] row-major (ldw=64).
// ---------------------------------------------------------------------------
template<int RELU, int PERHEAD>
__global__ __launch_bounds__(256) void gemm_bias(const float* __restrict__ A,
                                                 const float* __restrict__ W,
                                                 const float* __restrict__ bias,
                                                 float* __restrict__ C,
                                                 int N, int K) {
  __shared__ float As[16][64];   // As[k][m]
  __shared__ float Ws[16][64];   // Ws[k][n]
  const int tid = threadIdx.x;
  const int tx = tid & 15;       // n direction
  const int ty = tid >> 4;       // m direction
  const int bm = blockIdx.y << 6;
  const int bn = blockIdx.x << 6;
  const int ar = tid >> 2, akc = (tid & 3) << 2;   // A tile load
  const int wr = tid >> 4, wc = (tid & 15) << 2;   // W tile load
  const float* Wb; int ldw;
  if (PERHEAD) { Wb = W + (size_t)(bn >> 6) * K * 64; ldw = 64; }
  else         { Wb = W + bn;                         ldw = N;  }

  float acc[4][4] = {};
  for (int k0 = 0; k0 < K; k0 += 16) {
    float4 av = *(const float4*)(A + (size_t)(bm + ar) * K + k0 + akc);
    As[akc + 0][ar] = av.x; As[akc + 1][ar] = av.y;
    As[akc + 2][ar] = av.z; As[akc + 3][ar] = av.w;
    float4 wf = *(const float4*)(Wb + (size_t)(k0 + wr) * ldw + wc);
    *(float4*)&Ws[wr][wc] = wf;
    __syncthreads();
    #pragma unroll
    for (int kk = 0; kk < 16; ++kk) {
      float a0 = As[kk][(ty << 2) + 0], a1 = As[kk][(ty << 2) + 1];
      float a2 = As[kk][(ty << 2) + 2], a3 = As[kk][(ty << 2) + 3];
      float b0 = Ws[kk][(tx << 2) + 0], b1 = Ws[kk][(tx << 2) + 1];
      float c2 = Ws[kk][(tx << 2) + 2], b3 = Ws[kk][(tx << 2) + 3];
      acc[0][0] += a0*b0; acc[0][1] += a0*b1; acc[0][2] += a0*c2; acc[0][3] += a0*b3;
      acc[1][0] += a1*b0; acc[1][1] += a1*b1; acc[1][2] += a1*c2; acc[1][3] += a1*b3;
      acc[2][0] += a2*b0; acc[2][1] += a2*b1; acc[2][2] += a2*c2; acc[2][3] += a2*b3;
      acc[3][0] += a3*b0; acc[3][1] += a3*b1; acc[3][2] += a3*c2; acc[3][3] += a3*b3;
    }
    __syncthreads();
  }
  #pragma unroll
  for (int i = 0; i < 4; ++i) {
    const int m = bm + (ty << 2) + i;
    #pragma unroll
    for (int j = 0; j < 4; ++j) {
      const int n = bn + (tx << 2) + j;
      float c = acc[i][j] + bias[n];
      if (RELU) c = fmaxf(c, 0.0f);
      C[(size_t)m * N + n] = c;
    }
  }
}

// ---------------------------------------------------------------------------
// Fused attention: one block per (b, h, s_q). scores -> softmax -> @V.
// q,k,v,o layout: [B,S,H*DN] token-major, fp32.
// ---------------------------------------------------------------------------
__global__ __launch_bounds__(256) void attn(const float* __restrict__ q,
                                            const float* __restrict__ k,
                                            const float* __restrict__ v,
                                            const int* __restrict__ mask,
                                            float* __restrict__ o) {
  const int sq = blockIdx.x, hh = blockIdx.y, b = blockIdx.z;
  const int tid = threadIdx.x;
  __shared__ float qs[64];
  __shared__ float p[512];
  __shared__ float red[8];
  __shared__ float osum[4][64];

  const size_t rowq = ((size_t)(b * S_ + sq)) * D_ + hh * DN_;
  if (tid < 64) qs[tid] = q[rowq + tid];
  __syncthreads();

  float sc[2];
  #pragma unroll
  for (int r2 = 0; r2 < 2; ++r2) {
    const int t = tid + r2 * 256;
    const float* kp = k + ((size_t)(b * S_ + t)) * D_ + hh * DN_;
    float dot = 0.0f;
    #pragma unroll
    for (int e = 0; e < DN_; e += 4) {
      float4 kv = *(const float4*)(kp + e);
      dot += qs[e] * kv.x + qs[e+1] * kv.y + qs[e+2] * kv.z + qs[e+3] * kv.w;
    }
    const int mv = mask[((size_t)b * S_ + sq) * S_ + t];
    sc[r2] = dot * 0.125f + (float)mv * -1e9f;
  }
  // block max
  float mx = fmaxf(sc[0], sc[1]);
  #pragma unroll
  for (int off = 32; off > 0; off >>= 1) mx = fmaxf(mx, __shfl_down(mx, off));
  if ((tid & 63) == 0) red[tid >> 6] = mx;
  __syncthreads();
  if (tid == 0) red[4] = fmaxf(fmaxf(red[0], red[1]), fmaxf(red[2], red[3]));
  __syncthreads();
  const float m = red[4];
  float e0 = __expf(sc[0] - m), e1 = __expf(sc[1] - m);
  p[tid] = e0; p[tid + 256] = e1;
  // block sum
  float ss = e0 + e1;
  #pragma unroll
  for (int off = 32; off > 0; off >>= 1) ss += __shfl_down(ss, off);
  if ((tid & 63) == 0) red[tid >> 6] = ss;
  __syncthreads();
  if (tid == 0) red[5] = red[0] + red[1] + red[2] + red[3];
  __syncthreads();
  const float inv = 1.0f / red[5];

  // o[e] = sum_t p[t] * v[t,e]; 4 groups of 128 t each, e = lane
  const int e = tid & 63, g = tid >> 6;
  const float* vp = v + ((size_t)(b * S_ + g * 128)) * D_ + hh * DN_ + e;
  float oa = 0.0f;
  for (int t = 0; t < 128; ++t) oa += p[g * 128 + t] * vp[(size_t)t * D_];
  osum[g][e] = oa;
  __syncthreads();
  if (tid < 64)
    o[rowq + tid] = (osum[0][tid] + osum[1][tid] + osum[2][tid] + osum[3][tid]) * inv;
}

// ---------------------------------------------------------------------------
// h = LayerNorm(h + r) * g + be   (in place on h), one block per token
// ---------------------------------------------------------------------------
__global__ __launch_bounds__(256) void add_ln(float* __restrict__ h,
                                              const float* __restrict__ r,
                                              const float* __restrict__ g,
                                              const float* __restrict__ be) {
  const int t = blockIdx.x;
  const int tid = threadIdx.x;
  __shared__ float red[8];
  const size_t base = (size_t)t * D_;
  float x0 = h[base + tid]       + r[base + tid];
  float x1 = h[base + tid + 256] + r[base + tid + 256];
  float x2 = h[base + tid + 512] + r[base + tid + 512];
  float s = x0 + x1 + x2;
  #pragma unroll
  for (int off = 32; off > 0; off >>= 1) s += __shfl_down(s, off);
  if ((tid & 63) == 0) red[tid >> 6] = s;
  __syncthreads();
  if (tid == 0) red[4] = (red[0] + red[1] + red[2] + red[3]) * (1.0f / 768.0f);
  __syncthreads();
  const float m = red[4];
  float d0 = x0 - m, d1 = x1 - m, d2 = x2 - m;
  float s2 = d0*d0 + d1*d1 + d2*d2;
  #pragma unroll
  for (int off = 32; off > 0; off >>= 1) s2 += __shfl_down(s2, off);
  if ((tid & 63) == 0) red[tid >> 6] = s2;
  __syncthreads();
  if (tid == 0) red[5] = (red[0] + red[1] + red[2] + red[3]) * (1.0f / 768.0f);
  __syncthreads();
  const float rs = rsqrtf(red[5] + 1e-5f);
  h[base + tid]       = d0 * rs * g[tid]       + be[tid];
  h[base + tid + 256] = d1 * rs * g[tid + 256] + be[tid + 256];
  h[base + tid + 512] = d2 * rs * g[tid + 512] + be[tid + 512];
}

__global__ __launch_bounds__(256) void write_out(const float* __restrict__ h,
                                                 float* __restrict__ out, int n) {
  int i = blockIdx.x * 256 + threadIdx.x;
  if (i < n) out[i] = h[i];
}

// ---------------------------------------------------------------------------
extern "C" void kernel_launch(void* const* d_in, const int* in_sizes, int n_in,
                              void* d_out, int out_size, void* d_ws, size_t ws_size,
                              hipStream_t stream) {
  (void)in_sizes; (void)n_in; (void)out_size; (void)ws_size;
  const int* x    = (const int*)d_in[0];
  const int* mask = (const int*)d_in[1];
  const float* emb = (const float*)d_in[2];
  const float* Wq  = (const float*)d_in[3];
  const float* bq  = (const float*)d_in[4];
  const float* Wk  = (const float*)d_in[5];
  const float* bk  = (const float*)d_in[6];
  const float* Wv  = (const float*)d_in[7];
  const float* bv  = (const float*)d_in[8];
  const float* Wo  = (const float*)d_in[9];
  const float* bo  = (const float*)d_in[10];
  const float* W1  = (const float*)d_in[11];
  const float* b1  = (const float*)d_in[12];
  const float* W2  = (const float*)d_in[13];
  const float* b2  = (const float*)d_in[14];
  const float* g1  = (const float*)d_in[15];
  const float* be1 = (const float*)d_in[16];
  const float* g2  = (const float*)d_in[17];
  const float* be2 = (const float*)d_in[18];

  const size_t TD = (size_t)T_ * D_;   // 6,291,456 elements
  // Workspace: 6 fp32 [T,D] buffers = 144 MB, + probe flag.
  float* h  = (float*)d_ws;
  float* q  = h  + TD;
  float* kb = q  + TD;
  float* vb = kb + TD;
  float* o1 = vb + TD;
  float* o2 = o1 + TD;
  float* ff = q;   // ff [8192,3072] aliases q|kb|vb|o1 (exactly 4*TD floats)
  int* xstride = (int*)(o2 + TD);

  probe_x<<<dim3(1), 64, 0, stream>>>(x, xstride);
  embed_pe<<<dim3(T_), 256, 0, stream>>>(x, xstride, emb, h);

  const dim3 gD(D_ / 64, T_ / 64);   // N=768
  const dim3 gF(F_ / 64, T_ / 64);   // N=3072
  for (int l = 0; l < L_; ++l) {
    const size_t wDD = (size_t)l * D_ * D_;          // = l*H*D*DN for q/k/v too
    gemm_bias<0, 1><<<gD, 256, 0, stream>>>(h,  Wq + wDD, bq + l * D_, q,  D_, D_);
    gemm_bias<0, 1><<<gD, 256, 0, stream>>>(h,  Wk + wDD, bk + l * D_, kb, D_, D_);
    gemm_bias<0, 1><<<gD, 256, 0, stream>>>(h,  Wv + wDD, bv + l * D_, vb, D_, D_);
    attn<<<dim3(S_, H_, B_), 256, 0, stream>>>(q, kb, vb, mask, o1);
    gemm_bias<0, 0><<<gD, 256, 0, stream>>>(o1, Wo + wDD, bo + l * D_, o2, D_, D_);
    add_ln<<<dim3(T_), 256, 0, stream>>>(h, o2, g1 + l * D_, be1 + l * D_);
    gemm_bias<1, 0><<<gF, 256, 0, stream>>>(h,  W1 + (size_t)l * D_ * F_, b1 + l * F_, ff, F_, D_);
    gemm_bias<0, 0><<<gD, 256, 0, stream>>>(ff, W2 + (size_t)l * F_ * D_, b2 + l * D_, o2, D_, F_);
    add_ln<<<dim3(T_), 256, 0, stream>>>(h, o2, g2 + l * D_, be2 + l * D_);
  }
  write_out<<<dim3((unsigned)(TD / 256)), 256, 0, stream>>>(h, (float*)d_out, (int)TD);
}

// Round 4
// 3230.310 us; speedup vs baseline: 7.8484x; 7.8484x over previous
//
#include <hip/hip_runtime.h>
#include <hip/hip_bf16.h>
#include <math.h>

#define B_  16
#define S_  512
#define D_  768
#define H_  12
#define DN_ 64
#define F_  3072
#define L_  6
#define T_  (B_*S_)          // 8192 tokens

typedef unsigned short ushort_t;
typedef short short8 __attribute__((ext_vector_type(8)));
typedef float floatx4 __attribute__((ext_vector_type(4)));

static __device__ __forceinline__ float b2f(ushort_t u) {
  union { unsigned int i; float f; } x; x.i = ((unsigned int)u) << 16; return x.f;
}
static __device__ __forceinline__ ushort_t f2b(float f) {
  union { float f; unsigned int i; } x; x.f = f;
  unsigned int r = x.i + 0x7fffu + ((x.i >> 16) & 1u);   // RNE
  return (ushort_t)(r >> 16);
}

// ---------------------------------------------------------------------------
// Probe x dtype: int64 (stride 2) vs int32 (stride 1)
// ---------------------------------------------------------------------------
__global__ __launch_bounds__(64) void probe_x(const int* __restrict__ x,
                                              int* __restrict__ xstride) {
  if (threadIdx.x == 0) {
    int allzero = 1;
    for (int i = 0; i < 64; ++i) allzero &= (x[2 * i + 1] == 0) ? 1 : 0;
    *xstride = allzero ? 2 : 1;
  }
}

// ---------------------------------------------------------------------------
// Embedding + positional encoding -> h32 (fp32 spine) and h16 (bf16 GEMM in)
// ---------------------------------------------------------------------------
__global__ __launch_bounds__(256) void embed_pe(const int* __restrict__ x,
                                                const int* __restrict__ xstride,
                                                const float* __restrict__ emb,
                                                float* __restrict__ h32,
                                                ushort_t* __restrict__ h16) {
  const int t = blockIdx.x;
  const int s = t & (S_ - 1);
  const int tok = x[t * (*xstride)];
  const float* ep = emb + (size_t)tok * D_;
  const float pos = (float)s;
  for (int d = threadIdx.x; d < D_; d += 256) {
    float pe;
    if ((d & 1) == 0) {
      float freq = powf(10000.0f, -(float)d * (1.0f / 768.0f));
      pe = sinf(pos * freq);
    } else {
      float freq = powf(10000.0f, -(float)(d + 1) * (1.0f / 768.0f));
      pe = cosf(pos * freq);
    }
    float v = ep[d] + pe;
    h32[(size_t)t * D_ + d] = v;
    h16[(size_t)t * D_ + d] = f2b(v);
  }
}

// ---------------------------------------------------------------------------
// Batched transpose-cast: in fp32 [batch][R][C] -> out bf16 [batch][C][R]
// 32x32 LDS tile, coalesced both sides.
// ---------------------------------------------------------------------------
__global__ __launch_bounds__(256) void transpose_cast(const float* __restrict__ in,
                                                      ushort_t* __restrict__ out,
                                                      int R, int C) {
  __shared__ float tb[32][33];
  const int c0 = blockIdx.x * 32, r0 = blockIdx.y * 32;
  const float* ib = in + (size_t)blockIdx.z * R * C;
  ushort_t* ob = out + (size_t)blockIdx.z * R * C;
  const int i = threadIdx.x >> 5;   // 0..7
  const int j = threadIdx.x & 31;
  #pragma unroll
  for (int t = 0; t < 4; ++t)
    tb[i + 8 * t][j] = ib[(size_t)(r0 + i + 8 * t) * C + c0 + j];
  __syncthreads();
  #pragma unroll
  for (int t = 0; t < 4; ++t)
    ob[(size_t)(c0 + i + 8 * t) * R + r0 + j] = f2b(tb[j][i + 8 * t]);
}

// ---------------------------------------------------------------------------
// MFMA GEMM: C[M,N](bf16) = A[M,K](bf16) @ Bt[N,K](bf16)^T + bias(f32), RELU opt
// 128x128 tile, BK=32, 256 threads (4 waves), each wave 64x64 = 4x4 frags of
// v_mfma_f32_16x16x32_bf16.  A-frag: A[m=lane&15][k=quad*8+j]; B-frag:
// Bt[n=lane&15][k=quad*8+j]; C/D: col=lane&15, row=quad*4+reg.
// ---------------------------------------------------------------------------
template<int RELU>
__global__ __launch_bounds__(256) void gemm_mfma(const ushort_t* __restrict__ A,
                                                 const ushort_t* __restrict__ Bt,
                                                 const float* __restrict__ bias,
                                                 ushort_t* __restrict__ C,
                                                 int N, int K) {
  __shared__ ushort_t Alds[128 * 32];
  __shared__ ushort_t Blds[128 * 32];
  const int tid = threadIdx.x;
  const int lane = tid & 63, wave = tid >> 6;
  const int l16 = lane & 15, quad = lane >> 4;
  const int m0 = (wave >> 1) * 64, n0 = (wave & 1) * 64;
  const int bm = blockIdx.y * 128, bn = blockIdx.x * 128;
  const int r0 = tid >> 2, koff = (tid & 3) * 8;   // staging: 16B chunks

  floatx4 acc[4][4] = {};
  for (int k0 = 0; k0 < K; k0 += 32) {
    uint4 a0 = *(const uint4*)(A  + (size_t)(bm + r0)      * K + k0 + koff);
    uint4 a1 = *(const uint4*)(A  + (size_t)(bm + r0 + 64) * K + k0 + koff);
    uint4 b0 = *(const uint4*)(Bt + (size_t)(bn + r0)      * K + k0 + koff);
    uint4 b1 = *(const uint4*)(Bt + (size_t)(bn + r0 + 64) * K + k0 + koff);
    __syncthreads();
    *(uint4*)&Alds[(size_t)r0 * 32 + koff]        = a0;
    *(uint4*)&Alds[(size_t)(r0 + 64) * 32 + koff] = a1;
    *(uint4*)&Blds[(size_t)r0 * 32 + koff]        = b0;
    *(uint4*)&Blds[(size_t)(r0 + 64) * 32 + koff] = b1;
    __syncthreads();
    short8 af[4], bf[4];
    #pragma unroll
    for (int fi = 0; fi < 4; ++fi)
      af[fi] = *(const short8*)&Alds[(m0 + fi * 16 + l16) * 32 + quad * 8];
    #pragma unroll
    for (int fj = 0; fj < 4; ++fj)
      bf[fj] = *(const short8*)&Blds[(n0 + fj * 16 + l16) * 32 + quad * 8];
    #pragma unroll
    for (int fi = 0; fi < 4; ++fi)
      #pragma unroll
      for (int fj = 0; fj < 4; ++fj)
        acc[fi][fj] = __builtin_amdgcn_mfma_f32_16x16x32_bf16(af[fi], bf[fj], acc[fi][fj], 0, 0, 0);
  }
  #pragma unroll
  for (int fi = 0; fi < 4; ++fi) {
    #pragma unroll
    for (int fj = 0; fj < 4; ++fj) {
      const int row = bm + m0 + fi * 16 + quad * 4;
      const int col = bn + n0 + fj * 16 + l16;
      const float bv = bias[col];
      #pragma unroll
      for (int r = 0; r < 4; ++r) {
        float v = acc[fi][fj][r] + bv;
        if (RELU) v = fmaxf(v, 0.0f);
        C[(size_t)(row + r) * N + col] = f2b(v);
      }
    }
  }
}

// ---------------------------------------------------------------------------
// Flash-style attention: block per (q-tile 64, head, batch). 256 threads.
// ty=tid>>4 owns 4 q-rows, tx=tid&15 owns 4 cols. Online softmax.
// LDS tiles padded to stride 68 for conflict-free float4 fragment reads.
// ---------------------------------------------------------------------------
__global__ __launch_bounds__(256) void attn_tile(const ushort_t* __restrict__ q,
                                                 const ushort_t* __restrict__ k,
                                                 const ushort_t* __restrict__ v,
                                                 const int* __restrict__ mask,
                                                 ushort_t* __restrict__ o) {
  __shared__ float Qs[64][68];   // [e][q]
  __shared__ float Ks[64][68];   // [e][k]
  __shared__ float Vs[64][68];   // [k][e]
  __shared__ float Ps[64][68];   // [q][k]
  const int qt = blockIdx.x, hh = blockIdx.y, b = blockIdx.z;
  const int tid = threadIdx.x;
  const int ty = tid >> 4, tx = tid & 15;

  // stage Q tile (transposed [e][q])
  for (int c = tid; c < 1024; c += 256) {
    const int row = c >> 4, e0 = (c & 15) * 4;
    ushort4 qv = *(const ushort4*)(q + ((size_t)(b * S_ + qt * 64 + row)) * D_ + hh * 64 + e0);
    Qs[e0 + 0][row] = b2f(qv.x); Qs[e0 + 1][row] = b2f(qv.y);
    Qs[e0 + 2][row] = b2f(qv.z); Qs[e0 + 3][row] = b2f(qv.w);
  }

  float O[4][4] = {};
  float mrow[4] = {-3e38f, -3e38f, -3e38f, -3e38f};
  float lrow[4] = {};

  for (int kt = 0; kt < 8; ++kt) {
    __syncthreads();
    // stage K (transposed) and V (natural) tiles
    for (int c = tid; c < 1024; c += 256) {
      const int row = c >> 4, e0 = (c & 15) * 4;
      const size_t gro = ((size_t)(b * S_ + kt * 64 + row)) * D_ + hh * 64 + e0;
      ushort4 kv = *(const ushort4*)(k + gro);
      Ks[e0 + 0][row] = b2f(kv.x); Ks[e0 + 1][row] = b2f(kv.y);
      Ks[e0 + 2][row] = b2f(kv.z); Ks[e0 + 3][row] = b2f(kv.w);
      ushort4 vv = *(const ushort4*)(v + gro);
      *(float4*)&Vs[row][e0] = make_float4(b2f(vv.x), b2f(vv.y), b2f(vv.z), b2f(vv.w));
    }
    __syncthreads();

    // scores: s[i][j] = dot(Q[q],K[k])*0.125 + mask*-1e9   (init with bias*8)
    float s[4][4];
    #pragma unroll
    for (int i = 0; i < 4; ++i) {
      int4 mv = *(const int4*)(mask + ((size_t)(b * S_ + qt * 64 + ty * 4 + i)) * S_ + kt * 64 + tx * 4);
      s[i][0] = -8e9f * (float)mv.x; s[i][1] = -8e9f * (float)mv.y;
      s[i][2] = -8e9f * (float)mv.z; s[i][3] = -8e9f * (float)mv.w;
    }
    for (int e = 0; e < 64; ++e) {
      float4 av = *(const float4*)&Qs[e][ty * 4];
      float4 bv = *(const float4*)&Ks[e][tx * 4];
      float a[4] = {av.x, av.y, av.z, av.w};
      float bb[4] = {bv.x, bv.y, bv.z, bv.w};
      #pragma unroll
      for (int i = 0; i < 4; ++i)
        #pragma unroll
        for (int j = 0; j < 4; ++j)
          s[i][j] += a[i] * bb[j];
    }

    // online softmax update per q-row (reduce across 16 tx lanes)
    #pragma unroll
    for (int i = 0; i < 4; ++i) {
      float sc[4];
      #pragma unroll
      for (int j = 0; j < 4; ++j) sc[j] = s[i][j] * 0.125f;
      float mt = fmaxf(fmaxf(sc[0], sc[1]), fmaxf(sc[2], sc[3]));
      mt = fmaxf(mt, __shfl_xor(mt, 1)); mt = fmaxf(mt, __shfl_xor(mt, 2));
      mt = fmaxf(mt, __shfl_xor(mt, 4)); mt = fmaxf(mt, __shfl_xor(mt, 8));
      const float mn = fmaxf(mrow[i], mt);
      const float alpha = __expf(mrow[i] - mn);
      mrow[i] = mn;
      float p0 = __expf(sc[0] - mn), p1 = __expf(sc[1] - mn);
      float p2 = __expf(sc[2] - mn), p3 = __expf(sc[3] - mn);
      *(float4*)&Ps[ty * 4 + i][tx * 4] = make_float4(p0, p1, p2, p3);
      float rs = p0 + p1 + p2 + p3;
      rs += __shfl_xor(rs, 1); rs += __shfl_xor(rs, 2);
      rs += __shfl_xor(rs, 4); rs += __shfl_xor(rs, 8);
      lrow[i] = lrow[i] * alpha + rs;
      #pragma unroll
      for (int j = 0; j < 4; ++j) O[i][j] *= alpha;
    }
    __syncthreads();

    // O += P @ V
    for (int kk = 0; kk < 64; ++kk) {
      float a0 = Ps[ty * 4 + 0][kk], a1 = Ps[ty * 4 + 1][kk];
      float a2 = Ps[ty * 4 + 2][kk], a3 = Ps[ty * 4 + 3][kk];
      float4 vv = *(const float4*)&Vs[kk][tx * 4];
      O[0][0] += a0 * vv.x; O[0][1] += a0 * vv.y; O[0][2] += a0 * vv.z; O[0][3] += a0 * vv.w;
      O[1][0] += a1 * vv.x; O[1][1] += a1 * vv.y; O[1][2] += a1 * vv.z; O[1][3] += a1 * vv.w;
      O[2][0] += a2 * vv.x; O[2][1] += a2 * vv.y; O[2][2] += a2 * vv.z; O[2][3] += a2 * vv.w;
      O[3][0] += a3 * vv.x; O[3][1] += a3 * vv.y; O[3][2] += a3 * vv.z; O[3][3] += a3 * vv.w;
    }
  }

  #pragma unroll
  for (int i = 0; i < 4; ++i) {
    const float inv = 1.0f / lrow[i];
    ushort4 ov;
    ov.x = f2b(O[i][0] * inv); ov.y = f2b(O[i][1] * inv);
    ov.z = f2b(O[i][2] * inv); ov.w = f2b(O[i][3] * inv);
    *(ushort4*)(o + ((size_t)(b * S_ + qt * 64 + ty * 4 + i)) * D_ + hh * 64 + tx * 4) = ov;
  }
}

// ---------------------------------------------------------------------------
// h32 = LayerNorm(h32 + r(bf16)) * g + be ; also emit bf16 copy h16
// ---------------------------------------------------------------------------
__global__ __launch_bounds__(256) void add_ln(float* __restrict__ h,
                                              const ushort_t* __restrict__ r,
                                              const float* __restrict__ g,
                                              const float* __restrict__ be,
                                              ushort_t* __restrict__ h16) {
  const int t = blockIdx.x;
  const int tid = threadIdx.x;
  __shared__ float red[8];
  const size_t base = (size_t)t * D_;
  float x0 = h[base + tid]       + b2f(r[base + tid]);
  float x1 = h[base + tid + 256] + b2f(r[base + tid + 256]);
  float x2 = h[base + tid + 512] + b2f(r[base + tid + 512]);
  float s = x0 + x1 + x2;
  #pragma unroll
  for (int off = 32; off > 0; off >>= 1) s += __shfl_down(s, off);
  if ((tid & 63) == 0) red[tid >> 6] = s;
  __syncthreads();
  if (tid == 0) red[4] = (red[0] + red[1] + red[2] + red[3]) * (1.0f / 768.0f);
  __syncthreads();
  const float m = red[4];
  float d0 = x0 - m, d1 = x1 - m, d2 = x2 - m;
  float s2 = d0 * d0 + d1 * d1 + d2 * d2;
  #pragma unroll
  for (int off = 32; off > 0; off >>= 1) s2 += __shfl_down(s2, off);
  if ((tid & 63) == 0) red[tid >> 6] = s2;
  __syncthreads();
  if (tid == 0) red[5] = (red[0] + red[1] + red[2] + red[3]) * (1.0f / 768.0f);
  __syncthreads();
  const float rs = rsqrtf(red[5] + 1e-5f);
  float y0 = d0 * rs * g[tid]       + be[tid];
  float y1 = d1 * rs * g[tid + 256] + be[tid + 256];
  float y2 = d2 * rs * g[tid + 512] + be[tid + 512];
  h[base + tid]       = y0; h16[base + tid]       = f2b(y0);
  h[base + tid + 256] = y1; h16[base + tid + 256] = f2b(y1);
  h[base + tid + 512] = y2; h16[base + tid + 512] = f2b(y2);
}

__global__ __launch_bounds__(256) void write_out(const float* __restrict__ h,
                                                 float* __restrict__ out, int n) {
  int i = blockIdx.x * 256 + threadIdx.x;
  if (i < n) out[i] = h[i];
}

// ---------------------------------------------------------------------------
extern "C" void kernel_launch(void* const* d_in, const int* in_sizes, int n_in,
                              void* d_out, int out_size, void* d_ws, size_t ws_size,
                              hipStream_t stream) {
  (void)in_sizes; (void)n_in; (void)out_size; (void)ws_size;
  const int* x    = (const int*)d_in[0];
  const int* mask = (const int*)d_in[1];
  const float* emb = (const float*)d_in[2];
  const float* Wq  = (const float*)d_in[3];
  const float* bq  = (const float*)d_in[4];
  const float* Wk  = (const float*)d_in[5];
  const float* bk  = (const float*)d_in[6];
  const float* Wv  = (const float*)d_in[7];
  const float* bv  = (const float*)d_in[8];
  const float* Wo  = (const float*)d_in[9];
  const float* bo  = (const float*)d_in[10];
  const float* W1  = (const float*)d_in[11];
  const float* b1  = (const float*)d_in[12];
  const float* W2  = (const float*)d_in[13];
  const float* b2  = (const float*)d_in[14];
  const float* g1  = (const float*)d_in[15];
  const float* be1 = (const float*)d_in[16];
  const float* g2  = (const float*)d_in[17];
  const float* be2 = (const float*)d_in[18];

  const size_t TD = (size_t)T_ * D_;             // 6,291,456
  const size_t WDD = (size_t)L_ * D_ * D_;       // 3,538,944
  const size_t WDF = (size_t)L_ * D_ * F_;       // 14,155,776

  float* h32 = (float*)d_ws;                     // 24 MB
  ushort_t* h16 = (ushort_t*)(h32 + TD);
  ushort_t* q16 = h16 + TD;
  ushort_t* k16 = q16 + TD;
  ushort_t* v16 = k16 + TD;
  ushort_t* o1  = v16 + TD;
  ushort_t* o2  = o1 + TD;
  ushort_t* ff  = q16;                           // [8192,3072] aliases q,k,v,o1
  ushort_t* WqT = o2 + TD;
  ushort_t* WkT = WqT + WDD;
  ushort_t* WvT = WkT + WDD;
  ushort_t* WoT = WvT + WDD;
  ushort_t* W1T = WoT + WDD;
  ushort_t* W2T = W1T + WDF;
  int* xstride  = (int*)(W2T + WDF);

  probe_x<<<dim3(1), 64, 0, stream>>>(x, xstride);
  // weight transpose-casts: in [batch][R][C] fp32 -> out [batch][C][R] bf16
  transpose_cast<<<dim3(2, 24, 72), 256, 0, stream>>>(Wq, WqT, 768, 64);
  transpose_cast<<<dim3(2, 24, 72), 256, 0, stream>>>(Wk, WkT, 768, 64);
  transpose_cast<<<dim3(2, 24, 72), 256, 0, stream>>>(Wv, WvT, 768, 64);
  transpose_cast<<<dim3(24, 24, 6), 256, 0, stream>>>(Wo, WoT, 768, 768);
  transpose_cast<<<dim3(96, 24, 6), 256, 0, stream>>>(W1, W1T, 768, 3072);
  transpose_cast<<<dim3(24, 96, 6), 256, 0, stream>>>(W2, W2T, 3072, 768);
  embed_pe<<<dim3(T_), 256, 0, stream>>>(x, xstride, emb, h32, h16);

  const dim3 gD(D_ / 128, T_ / 128);   // 6 x 64
  const dim3 gF(F_ / 128, T_ / 128);   // 24 x 64
  for (int l = 0; l < L_; ++l) {
    const size_t oDD = (size_t)l * D_ * D_;
    const size_t oDF = (size_t)l * D_ * F_;
    gemm_mfma<0><<<gD, 256, 0, stream>>>(h16, WqT + oDD, bq + l * D_, q16, D_, D_);
    gemm_mfma<0><<<gD, 256, 0, stream>>>(h16, WkT + oDD, bk + l * D_, k16, D_, D_);
    gemm_mfma<0><<<gD, 256, 0, stream>>>(h16, WvT + oDD, bv + l * D_, v16, D_, D_);
    attn_tile<<<dim3(8, H_, B_), 256, 0, stream>>>(q16, k16, v16, mask, o1);
    gemm_mfma<0><<<gD, 256, 0, stream>>>(o1, WoT + oDD, bo + l * D_, o2, D_, D_);
    add_ln<<<dim3(T_), 256, 0, stream>>>(h32, o2, g1 + l * D_, be1 + l * D_, h16);
    gemm_mfma<1><<<gF, 256, 0, stream>>>(h16, W1T + oDF, b1 + l * F_, ff, F_, D_);
    gemm_mfma<0><<<gD, 256, 0, stream>>>(ff, W2T + oDF, b2 + l * D_, o2, D_, F_);
    add_ln<<<dim3(T_), 256, 0, stream>>>(h32, o2, g2 + l * D_, be2 + l * D_, h16);
  }
  write_out<<<dim3((unsigned)(TD / 256)), 256, 0, stream>>>(h32, (float*)d_out, (int)TD);
}

// Round 5
// 2366.962 us; speedup vs baseline: 10.7111x; 1.3647x over previous
//
#include <hip/hip_runtime.h>
#include <hip/hip_bf16.h>
#include <math.h>

#define B_  16
#define S_  512
#define D_  768
#define H_  12
#define DN_ 64
#define F_  3072
#define L_  6
#define T_  (B_*S_)          // 8192 tokens

typedef unsigned short ushort_t;
typedef short short8 __attribute__((ext_vector_type(8)));
typedef float floatx4 __attribute__((ext_vector_type(4)));

#define LDS_AS(p) ((__attribute__((address_space(3))) void*)(p))
#define GLB_AS(p) ((const __attribute__((address_space(1))) void*)(p))

static __device__ __forceinline__ float b2f(ushort_t u) {
  union { unsigned int i; float f; } x; x.i = ((unsigned int)u) << 16; return x.f;
}
static __device__ __forceinline__ ushort_t f2b(float f) {
  union { float f; unsigned int i; } x; x.f = f;
  unsigned int r = x.i + 0x7fffu + ((x.i >> 16) & 1u);   // RNE
  return (ushort_t)(r >> 16);
}

// ---------------------------------------------------------------------------
// Probe x dtype: int64 (stride 2) vs int32 (stride 1)
// ---------------------------------------------------------------------------
__global__ __launch_bounds__(64) void probe_x(const int* __restrict__ x,
                                              int* __restrict__ xstride) {
  if (threadIdx.x == 0) {
    int allzero = 1;
    for (int i = 0; i < 64; ++i) allzero &= (x[2 * i + 1] == 0) ? 1 : 0;
    *xstride = allzero ? 2 : 1;
  }
}

// ---------------------------------------------------------------------------
// Embedding + positional encoding -> h32 (fp32 spine) and h16 (bf16)
// ---------------------------------------------------------------------------
__global__ __launch_bounds__(256) void embed_pe(const int* __restrict__ x,
                                                const int* __restrict__ xstride,
                                                const float* __restrict__ emb,
                                                float* __restrict__ h32,
                                                ushort_t* __restrict__ h16) {
  const int t = blockIdx.x;
  const int s = t & (S_ - 1);
  const int tok = x[t * (*xstride)];
  const float* ep = emb + (size_t)tok * D_;
  const float pos = (float)s;
  for (int d = threadIdx.x; d < D_; d += 256) {
    float pe;
    if ((d & 1) == 0) {
      float freq = powf(10000.0f, -(float)d * (1.0f / 768.0f));
      pe = sinf(pos * freq);
    } else {
      float freq = powf(10000.0f, -(float)(d + 1) * (1.0f / 768.0f));
      pe = cosf(pos * freq);
    }
    float v = ep[d] + pe;
    h32[(size_t)t * D_ + d] = v;
    h16[(size_t)t * D_ + d] = f2b(v);
  }
}

// ---------------------------------------------------------------------------
// mask int32 -> bf16 bias (0 or -1e9), 4 elements/thread
// ---------------------------------------------------------------------------
__global__ __launch_bounds__(256) void mask_bias(const int* __restrict__ mask,
                                                 ushort_t* __restrict__ bias) {
  const size_t i = ((size_t)blockIdx.x * 256 + threadIdx.x) * 4;
  int4 m = *(const int4*)(mask + i);
  ushort4 o;
  o.x = m.x ? f2b(-1e9f) : (ushort_t)0;
  o.y = m.y ? f2b(-1e9f) : (ushort_t)0;
  o.z = m.z ? f2b(-1e9f) : (ushort_t)0;
  o.w = m.w ? f2b(-1e9f) : (ushort_t)0;
  *(ushort4*)(bias + i) = o;
}

// ---------------------------------------------------------------------------
// Batched transpose-cast: fp32 [batch][R][C] -> bf16 [batch][C][R]
// ---------------------------------------------------------------------------
__global__ __launch_bounds__(256) void transpose_cast(const float* __restrict__ in,
                                                      ushort_t* __restrict__ out,
                                                      int R, int C) {
  __shared__ float tb[32][33];
  const int c0 = blockIdx.x * 32, r0 = blockIdx.y * 32;
  const float* ib = in + (size_t)blockIdx.z * R * C;
  ushort_t* ob = out + (size_t)blockIdx.z * R * C;
  const int i = threadIdx.x >> 5;
  const int j = threadIdx.x & 31;
  #pragma unroll
  for (int t = 0; t < 4; ++t)
    tb[i + 8 * t][j] = ib[(size_t)(r0 + i + 8 * t) * C + c0 + j];
  __syncthreads();
  #pragma unroll
  for (int t = 0; t < 4; ++t)
    ob[(size_t)(c0 + i + 8 * t) * R + r0 + j] = f2b(tb[j][i + 8 * t]);
}

// ---------------------------------------------------------------------------
// v16 [B*S][H*64] bf16 -> vT [B*H][64 e][512 s] bf16
// ---------------------------------------------------------------------------
__global__ __launch_bounds__(256) void transpose_v(const ushort_t* __restrict__ v,
                                                   ushort_t* __restrict__ vT) {
  __shared__ ushort_t tb[32][33];
  const int s0 = blockIdx.x * 32, e0 = blockIdx.y * 32;
  const int bh = blockIdx.z;             // b*12+h
  const int b = bh / 12, hh = bh - b * 12;
  const int i = threadIdx.x >> 5, j = threadIdx.x & 31;
  #pragma unroll
  for (int t = 0; t < 4; ++t)
    tb[i + 8 * t][j] = v[((size_t)(b * S_ + s0 + i + 8 * t)) * D_ + hh * 64 + e0 + j];
  __syncthreads();
  #pragma unroll
  for (int t = 0; t < 4; ++t)
    vT[((size_t)(bh * 64 + e0 + i + 8 * t)) * S_ + s0 + j] = tb[j][i + 8 * t];
}

// ---------------------------------------------------------------------------
// MFMA GEMM: C[M,N](bf16) = A[M,K](bf16) @ Bt[N,K]^T + bias(f32), RELU opt.
// 128x128 tile, BK=32, 4 waves. Staging via global_load_lds width 16
// (LDS dest == wave base + lane*16 with the unpadded [row][32] layout).
// ---------------------------------------------------------------------------
template<int RELU>
__global__ __launch_bounds__(256) void gemm_mfma(const ushort_t* __restrict__ A,
                                                 const ushort_t* __restrict__ Bt,
                                                 const float* __restrict__ bias,
                                                 ushort_t* __restrict__ C,
                                                 int N, int K) {
  __shared__ ushort_t Alds[128 * 32];
  __shared__ ushort_t Blds[128 * 32];
  const int tid = threadIdx.x;
  const int lane = tid & 63, wave = tid >> 6;
  const int l16 = lane & 15, quad = lane >> 4;
  const int m0 = (wave >> 1) * 64, n0 = (wave & 1) * 64;
  const int bm = blockIdx.y * 128, bn = blockIdx.x * 128;
  const int r0 = tid >> 2, koff = (tid & 3) * 8;

  const ushort_t* ga0 = A  + (size_t)(bm + r0) * K + koff;
  const ushort_t* ga1 = ga0 + (size_t)64 * K;
  const ushort_t* gb0 = Bt + (size_t)(bn + r0) * K + koff;
  const ushort_t* gb1 = gb0 + (size_t)64 * K;
  ushort_t* la0 = &Alds[tid * 8];
  ushort_t* la1 = &Alds[64 * 32 + tid * 8];
  ushort_t* lb0 = &Blds[tid * 8];
  ushort_t* lb1 = &Blds[64 * 32 + tid * 8];

  floatx4 acc[4][4] = {};
  for (int k0 = 0; k0 < K; k0 += 32) {
    __syncthreads();
    __builtin_amdgcn_global_load_lds(GLB_AS(ga0 + k0), LDS_AS(la0), 16, 0, 0);
    __builtin_amdgcn_global_load_lds(GLB_AS(ga1 + k0), LDS_AS(la1), 16, 0, 0);
    __builtin_amdgcn_global_load_lds(GLB_AS(gb0 + k0), LDS_AS(lb0), 16, 0, 0);
    __builtin_amdgcn_global_load_lds(GLB_AS(gb1 + k0), LDS_AS(lb1), 16, 0, 0);
    __syncthreads();
    short8 af[4], bf[4];
    #pragma unroll
    for (int fi = 0; fi < 4; ++fi)
      af[fi] = *(const short8*)&Alds[(m0 + fi * 16 + l16) * 32 + quad * 8];
    #pragma unroll
    for (int fj = 0; fj < 4; ++fj)
      bf[fj] = *(const short8*)&Blds[(n0 + fj * 16 + l16) * 32 + quad * 8];
    #pragma unroll
    for (int fi = 0; fi < 4; ++fi)
      #pragma unroll
      for (int fj = 0; fj < 4; ++fj)
        acc[fi][fj] = __builtin_amdgcn_mfma_f32_16x16x32_bf16(af[fi], bf[fj], acc[fi][fj], 0, 0, 0);
  }
  #pragma unroll
  for (int fi = 0; fi < 4; ++fi) {
    #pragma unroll
    for (int fj = 0; fj < 4; ++fj) {
      const int row = bm + m0 + fi * 16 + quad * 4;
      const int col = bn + n0 + fj * 16 + l16;
      const float bv = bias[col];
      #pragma unroll
      for (int r = 0; r < 4; ++r) {
        float v = acc[fi][fj][r] + bv;
        if (RELU) v = fmaxf(v, 0.0f);
        C[(size_t)(row + r) * N + col] = f2b(v);
      }
    }
  }
}

// ---------------------------------------------------------------------------
// MFMA flash attention. Block per (qtile=64, head, batch); 4 waves, wave w
// owns q-strip [w*16, w*16+16). QK^T and PV via mfma_16x16x32_bf16.
// S C-layout rows = quad*4+r -> row stats via shfl_xor over 16 l16 lanes.
// P goes C->A layout through a per-wave-private LDS strip (no barrier).
// ---------------------------------------------------------------------------
__global__ __launch_bounds__(256) void attn_mfma(const ushort_t* __restrict__ q,
                                                 const ushort_t* __restrict__ k,
                                                 const ushort_t* __restrict__ vT,
                                                 const ushort_t* __restrict__ bias,
                                                 ushort_t* __restrict__ o) {
  __shared__ ushort_t Qs[64][72];
  __shared__ ushort_t Ks[64][72];
  __shared__ ushort_t Vt[64][72];
  __shared__ ushort_t Ps[64][72];
  const int qt = blockIdx.x, hh = blockIdx.y, b = blockIdx.z;
  const int tid = threadIdx.x;
  const int lane = tid & 63, w = tid >> 6;
  const int l16 = lane & 15, quad = lane >> 4;

  // stage Q (natural [q][e])
  for (int c = tid; c < 1024; c += 256) {
    const int row = c >> 4, e0 = (c & 15) * 4;
    *(ushort4*)&Qs[row][e0] =
        *(const ushort4*)(q + ((size_t)(b * S_ + qt * 64 + row)) * D_ + hh * 64 + e0);
  }

  floatx4 Oa[4] = {};
  float mrow[4] = {-3e38f, -3e38f, -3e38f, -3e38f};
  float lrow[4] = {};
  const ushort_t* vbase = vT + ((size_t)(b * H_ + hh) * 64) * S_;   // [e][S]

  for (int kt = 0; kt < 8; ++kt) {
    __syncthreads();
    for (int c = tid; c < 1024; c += 256) {
      const int row = c >> 4, e0 = (c & 15) * 4;
      *(ushort4*)&Ks[row][e0] =
          *(const ushort4*)(k + ((size_t)(b * S_ + kt * 64 + row)) * D_ + hh * 64 + e0);
      *(ushort4*)&Vt[row][e0] =
          *(const ushort4*)(vbase + (size_t)row * S_ + kt * 64 + e0);
    }
    __syncthreads();

    // S = Q K^T  (A: m=q, k=e ; B: n=kcol, k=e)
    floatx4 sa[4] = {};
    #pragma unroll
    for (int st = 0; st < 2; ++st) {
      short8 aq = *(const short8*)&Qs[w * 16 + l16][st * 32 + quad * 8];
      #pragma unroll
      for (int fj = 0; fj < 4; ++fj) {
        short8 bk = *(const short8*)&Ks[fj * 16 + l16][st * 32 + quad * 8];
        sa[fj] = __builtin_amdgcn_mfma_f32_16x16x32_bf16(aq, bk, sa[fj], 0, 0, 0);
      }
    }

    // bias + online softmax (rows quad*4+r, cols fj*16+l16)
    #pragma unroll
    for (int r = 0; r < 4; ++r) {
      const int qrow = qt * 64 + w * 16 + quad * 4 + r;
      const ushort_t* bp = bias + ((size_t)b * S_ + qrow) * S_ + kt * 64 + l16;
      float s0 = sa[0][r] * 0.125f + b2f(bp[0]);
      float s1 = sa[1][r] * 0.125f + b2f(bp[16]);
      float s2 = sa[2][r] * 0.125f + b2f(bp[32]);
      float s3 = sa[3][r] * 0.125f + b2f(bp[48]);
      float mt = fmaxf(fmaxf(s0, s1), fmaxf(s2, s3));
      mt = fmaxf(mt, __shfl_xor(mt, 1)); mt = fmaxf(mt, __shfl_xor(mt, 2));
      mt = fmaxf(mt, __shfl_xor(mt, 4)); mt = fmaxf(mt, __shfl_xor(mt, 8));
      const float mn = fmaxf(mrow[r], mt);
      const float alpha = __expf(mrow[r] - mn);
      mrow[r] = mn;
      float p0 = __expf(s0 - mn), p1 = __expf(s1 - mn);
      float p2 = __expf(s2 - mn), p3 = __expf(s3 - mn);
      const int prow = w * 16 + quad * 4 + r;
      Ps[prow][ 0 + l16] = f2b(p0);
      Ps[prow][16 + l16] = f2b(p1);
      Ps[prow][32 + l16] = f2b(p2);
      Ps[prow][48 + l16] = f2b(p3);
      float rs = p0 + p1 + p2 + p3;
      rs += __shfl_xor(rs, 1); rs += __shfl_xor(rs, 2);
      rs += __shfl_xor(rs, 4); rs += __shfl_xor(rs, 8);
      lrow[r] = lrow[r] * alpha + rs;
      Oa[0][r] *= alpha; Oa[1][r] *= alpha; Oa[2][r] *= alpha; Oa[3][r] *= alpha;
    }

    // O += P V   (A: m=q, k=kcol from Ps ; B: n=e, k=kcol from Vt)
    #pragma unroll
    for (int st = 0; st < 2; ++st) {
      short8 ap = *(const short8*)&Ps[w * 16 + l16][st * 32 + quad * 8];
      #pragma unroll
      for (int fe = 0; fe < 4; ++fe) {
        short8 bv = *(const short8*)&Vt[fe * 16 + l16][st * 32 + quad * 8];
        Oa[fe] = __builtin_amdgcn_mfma_f32_16x16x32_bf16(ap, bv, Oa[fe], 0, 0, 0);
      }
    }
  }

  #pragma unroll
  for (int r = 0; r < 4; ++r) {
    const float inv = 1.0f / lrow[r];
    const size_t tok = (size_t)(b * S_ + qt * 64 + w * 16 + quad * 4 + r);
    #pragma unroll
    for (int fe = 0; fe < 4; ++fe)
      o[tok * D_ + hh * 64 + fe * 16 + l16] = f2b(Oa[fe][r] * inv);
  }
}

// ---------------------------------------------------------------------------
// h32 = LayerNorm(h32 + r(bf16)) * g + be ; also emit bf16 copy h16
// ---------------------------------------------------------------------------
__global__ __launch_bounds__(256) void add_ln(float* __restrict__ h,
                                              const ushort_t* __restrict__ r,
                                              const float* __restrict__ g,
                                              const float* __restrict__ be,
                                              ushort_t* __restrict__ h16) {
  const int t = blockIdx.x;
  const int tid = threadIdx.x;
  __shared__ float red[8];
  const size_t base = (size_t)t * D_;
  float x0 = h[base + tid]       + b2f(r[base + tid]);
  float x1 = h[base + tid + 256] + b2f(r[base + tid + 256]);
  float x2 = h[base + tid + 512] + b2f(r[base + tid + 512]);
  float s = x0 + x1 + x2;
  #pragma unroll
  for (int off = 32; off > 0; off >>= 1) s += __shfl_down(s, off);
  if ((tid & 63) == 0) red[tid >> 6] = s;
  __syncthreads();
  if (tid == 0) red[4] = (red[0] + red[1] + red[2] + red[3]) * (1.0f / 768.0f);
  __syncthreads();
  const float m = red[4];
  float d0 = x0 - m, d1 = x1 - m, d2 = x2 - m;
  float s2 = d0 * d0 + d1 * d1 + d2 * d2;
  #pragma unroll
  for (int off = 32; off > 0; off >>= 1) s2 += __shfl_down(s2, off);
  if ((tid & 63) == 0) red[tid >> 6] = s2;
  __syncthreads();
  if (tid == 0) red[5] = (red[0] + red[1] + red[2] + red[3]) * (1.0f / 768.0f);
  __syncthreads();
  const float rs = rsqrtf(red[5] + 1e-5f);
  float y0 = d0 * rs * g[tid]       + be[tid];
  float y1 = d1 * rs * g[tid + 256] + be[tid + 256];
  float y2 = d2 * rs * g[tid + 512] + be[tid + 512];
  h[base + tid]       = y0; h16[base + tid]       = f2b(y0);
  h[base + tid + 256] = y1; h16[base + tid + 256] = f2b(y1);
  h[base + tid + 512] = y2; h16[base + tid + 512] = f2b(y2);
}

__global__ __launch_bounds__(256) void write_out(const float* __restrict__ h,
                                                 float* __restrict__ out, int n) {
  int i = blockIdx.x * 256 + threadIdx.x;
  if (i < n) out[i] = h[i];
}

// ---------------------------------------------------------------------------
extern "C" void kernel_launch(void* const* d_in, const int* in_sizes, int n_in,
                              void* d_out, int out_size, void* d_ws, size_t ws_size,
                              hipStream_t stream) {
  (void)in_sizes; (void)n_in; (void)out_size; (void)ws_size;
  const int* x    = (const int*)d_in[0];
  const int* mask = (const int*)d_in[1];
  const float* emb = (const float*)d_in[2];
  const float* Wq  = (const float*)d_in[3];
  const float* bq  = (const float*)d_in[4];
  const float* Wk  = (const float*)d_in[5];
  const float* bk  = (const float*)d_in[6];
  const float* Wv  = (const float*)d_in[7];
  const float* bv  = (const float*)d_in[8];
  const float* Wo  = (const float*)d_in[9];
  const float* bo  = (const float*)d_in[10];
  const float* W1  = (const float*)d_in[11];
  const float* b1  = (const float*)d_in[12];
  const float* W2  = (const float*)d_in[13];
  const float* b2  = (const float*)d_in[14];
  const float* g1  = (const float*)d_in[15];
  const float* be1 = (const float*)d_in[16];
  const float* g2  = (const float*)d_in[17];
  const float* be2 = (const float*)d_in[18];

  const size_t TD  = (size_t)T_ * D_;            // 6,291,456
  const size_t WDD = (size_t)L_ * D_ * D_;       // 3,538,944
  const size_t WDF = (size_t)L_ * D_ * F_;       // 14,155,776

  float* h32 = (float*)d_ws;                     // 24 MB
  ushort_t* h16 = (ushort_t*)(h32 + TD);
  ushort_t* q16 = h16 + TD;
  ushort_t* k16 = q16 + TD;
  ushort_t* v16 = k16 + TD;
  ushort_t* o1  = v16 + TD;
  ushort_t* o2  = o1 + TD;
  ushort_t* ff  = q16;                           // aliases q,k,v,o1
  ushort_t* vT  = o2 + TD;                       // [B*H][64][512]
  ushort_t* bias16 = vT + TD;                    // [B][S][S]
  ushort_t* WqT = bias16 + (size_t)B_ * S_ * S_;
  ushort_t* WkT = WqT + WDD;
  ushort_t* WvT = WkT + WDD;
  ushort_t* WoT = WvT + WDD;
  ushort_t* W1T = WoT + WDD;
  ushort_t* W2T = W1T + WDF;
  int* xstride  = (int*)(W2T + WDF);

  probe_x<<<dim3(1), 64, 0, stream>>>(x, xstride);
  transpose_cast<<<dim3(2, 24, 72), 256, 0, stream>>>(Wq, WqT, 768, 64);
  transpose_cast<<<dim3(2, 24, 72), 256, 0, stream>>>(Wk, WkT, 768, 64);
  transpose_cast<<<dim3(2, 24, 72), 256, 0, stream>>>(Wv, WvT, 768, 64);
  transpose_cast<<<dim3(24, 24, 6), 256, 0, stream>>>(Wo, WoT, 768, 768);
  transpose_cast<<<dim3(96, 24, 6), 256, 0, stream>>>(W1, W1T, 768, 3072);
  transpose_cast<<<dim3(24, 96, 6), 256, 0, stream>>>(W2, W2T, 3072, 768);
  mask_bias<<<dim3((B_ * S_ * S_) / 1024), 256, 0, stream>>>(mask, bias16);
  embed_pe<<<dim3(T_), 256, 0, stream>>>(x, xstride, emb, h32, h16);

  const dim3 gD(D_ / 128, T_ / 128);   // 6 x 64
  const dim3 gF(F_ / 128, T_ / 128);   // 24 x 64
  for (int l = 0; l < L_; ++l) {
    const size_t oDD = (size_t)l * D_ * D_;
    const size_t oDF = (size_t)l * D_ * F_;
    gemm_mfma<0><<<gD, 256, 0, stream>>>(h16, WqT + oDD, bq + l * D_, q16, D_, D_);
    gemm_mfma<0><<<gD, 256, 0, stream>>>(h16, WkT + oDD, bk + l * D_, k16, D_, D_);
    gemm_mfma<0><<<gD, 256, 0, stream>>>(h16, WvT + oDD, bv + l * D_, v16, D_, D_);
    transpose_v<<<dim3(16, 2, B_ * H_), 256, 0, stream>>>(v16, vT);
    attn_mfma<<<dim3(8, H_, B_), 256, 0, stream>>>(q16, k16, vT, bias16, o1);
    gemm_mfma<0><<<gD, 256, 0, stream>>>(o1, WoT + oDD, bo + l * D_, o2, D_, D_);
    add_ln<<<dim3(T_), 256, 0, stream>>>(h32, o2, g1 + l * D_, be1 + l * D_, h16);
    gemm_mfma<1><<<gF, 256, 0, stream>>>(h16, W1T + oDF, b1 + l * F_, ff, F_, D_);
    gemm_mfma<0><<<gD, 256, 0, stream>>>(ff, W2T + oDF, b2 + l * D_, o2, D_, F_);
    add_ln<<<dim3(T_), 256, 0, stream>>>(h32, o2, g2 + l * D_, be2 + l * D_, h16);
  }
  write_out<<<dim3((unsigned)(TD / 256)), 256, 0, stream>>>(h32, (float*)d_out, (int)TD);
}

// Round 6
// 2148.327 us; speedup vs baseline: 11.8012x; 1.1018x over previous
//
#include <hip/hip_runtime.h>
#include <hip/hip_bf16.h>
#include <math.h>

#define B_  16
#define S_  512
#define D_  768
#define H_  12
#define DN_ 64
#define F_  3072
#define L_  6
#define T_  (B_*S_)          // 8192 tokens
#define QKVN 2304            // 3*D

typedef unsigned short ushort_t;
typedef short short8 __attribute__((ext_vector_type(8)));
typedef float floatx4 __attribute__((ext_vector_type(4)));

#define LDS_AS(p) ((__attribute__((address_space(3))) void*)(p))
#define GLB_AS(p) ((const __attribute__((address_space(1))) void*)(p))

static __device__ __forceinline__ float b2f(ushort_t u) {
  union { unsigned int i; float f; } x; x.i = ((unsigned int)u) << 16; return x.f;
}
static __device__ __forceinline__ ushort_t f2b(float f) {
  union { float f; unsigned int i; } x; x.f = f;
  unsigned int r = x.i + 0x7fffu + ((x.i >> 16) & 1u);   // RNE
  return (ushort_t)(r >> 16);
}

// ---------------------------------------------------------------------------
__global__ __launch_bounds__(64) void probe_x(const int* __restrict__ x,
                                              int* __restrict__ xstride) {
  if (threadIdx.x == 0) {
    int allzero = 1;
    for (int i = 0; i < 64; ++i) allzero &= (x[2 * i + 1] == 0) ? 1 : 0;
    *xstride = allzero ? 2 : 1;
  }
}

// ---------------------------------------------------------------------------
__global__ __launch_bounds__(256) void embed_pe(const int* __restrict__ x,
                                                const int* __restrict__ xstride,
                                                const float* __restrict__ emb,
                                                float* __restrict__ h32,
                                                ushort_t* __restrict__ h16) {
  const int t = blockIdx.x;
  const int s = t & (S_ - 1);
  const int tok = x[t * (*xstride)];
  const float* ep = emb + (size_t)tok * D_;
  const float pos = (float)s;
  for (int d = threadIdx.x; d < D_; d += 256) {
    float pe;
    if ((d & 1) == 0) {
      float freq = powf(10000.0f, -(float)d * (1.0f / 768.0f));
      pe = sinf(pos * freq);
    } else {
      float freq = powf(10000.0f, -(float)(d + 1) * (1.0f / 768.0f));
      pe = cosf(pos * freq);
    }
    float v = ep[d] + pe;
    h32[(size_t)t * D_ + d] = v;
    h16[(size_t)t * D_ + d] = f2b(v);
  }
}

// ---------------------------------------------------------------------------
__global__ __launch_bounds__(256) void mask_bias(const int* __restrict__ mask,
                                                 ushort_t* __restrict__ bias) {
  const size_t i = ((size_t)blockIdx.x * 256 + threadIdx.x) * 4;
  int4 m = *(const int4*)(mask + i);
  ushort4 o;
  o.x = m.x ? f2b(-1e9f) : (ushort_t)0;
  o.y = m.y ? f2b(-1e9f) : (ushort_t)0;
  o.z = m.z ? f2b(-1e9f) : (ushort_t)0;
  o.w = m.w ? f2b(-1e9f) : (ushort_t)0;
  *(ushort4*)(bias + i) = o;
}

// ---------------------------------------------------------------------------
// pack bq/bk/bv [L][768] each -> bqkv [L][2304]
// ---------------------------------------------------------------------------
__global__ __launch_bounds__(256) void pack_bias(const float* __restrict__ bq,
                                                 const float* __restrict__ bk,
                                                 const float* __restrict__ bv,
                                                 float* __restrict__ bqkv) {
  const int i = blockIdx.x * 256 + threadIdx.x;   // l*768+c, i < 4608
  if (i < L_ * D_) {
    const int l = i / D_, c = i - l * D_;
    bqkv[(size_t)l * QKVN + c]          = bq[i];
    bqkv[(size_t)l * QKVN + 768 + c]    = bk[i];
    bqkv[(size_t)l * QKVN + 1536 + c]   = bv[i];
  }
}

// ---------------------------------------------------------------------------
// Batched transpose-cast fp32 [z][R][C] -> bf16 out rows: for batch z,
// destination base = (z/ZH)*strideL + (z%ZH)*strideH; out[c][r] row len R.
// ---------------------------------------------------------------------------
__global__ __launch_bounds__(256) void transpose_cast(const float* __restrict__ in,
                                                      ushort_t* __restrict__ out,
                                                      int R, int C, int ZH,
                                                      size_t strideL, size_t strideH) {
  __shared__ float tb[32][33];
  const int c0 = blockIdx.x * 32, r0 = blockIdx.y * 32;
  const int z = blockIdx.z;
  const float* ib = in + (size_t)z * R * C;
  ushort_t* ob = out + (size_t)(z / ZH) * strideL + (size_t)(z % ZH) * strideH;
  const int i = threadIdx.x >> 5;
  const int j = threadIdx.x & 31;
  #pragma unroll
  for (int t = 0; t < 4; ++t)
    tb[i + 8 * t][j] = ib[(size_t)(r0 + i + 8 * t) * C + c0 + j];
  __syncthreads();
  #pragma unroll
  for (int t = 0; t < 4; ++t)
    ob[(size_t)(c0 + i + 8 * t) * R + r0 + j] = f2b(tb[j][i + 8 * t]);
}

// ---------------------------------------------------------------------------
// qkv [B*S][2304] (v at +1536) -> vT [B*H][64 e][512 s]
// ---------------------------------------------------------------------------
__global__ __launch_bounds__(256) void transpose_v(const ushort_t* __restrict__ qkv,
                                                   ushort_t* __restrict__ vT) {
  __shared__ ushort_t tb[32][33];
  const int s0 = blockIdx.x * 32, e0 = blockIdx.y * 32;
  const int bh = blockIdx.z;
  const int b = bh / 12, hh = bh - b * 12;
  const int i = threadIdx.x >> 5, j = threadIdx.x & 31;
  #pragma unroll
  for (int t = 0; t < 4; ++t)
    tb[i + 8 * t][j] = qkv[((size_t)(b * S_ + s0 + i + 8 * t)) * QKVN + 1536 + hh * 64 + e0 + j];
  __syncthreads();
  #pragma unroll
  for (int t = 0; t < 4; ++t)
    vT[((size_t)(bh * 64 + e0 + i + 8 * t)) * S_ + s0 + j] = tb[j][i + 8 * t];
}

// ---------------------------------------------------------------------------
// MFMA GEMM: C[M,N](bf16) = A[M,K](bf16) @ Bt[N,K]^T + bias(f32), RELU opt.
// 128x128 tile, BK=32, 4 waves, global_load_lds width-16 staging.
// L2 swizzle: groups of 8 M-blocks sweep all N-blocks before advancing.
// ---------------------------------------------------------------------------
template<int RELU>
__global__ __launch_bounds__(256) void gemm_mfma(const ushort_t* __restrict__ A,
                                                 const ushort_t* __restrict__ Bt,
                                                 const float* __restrict__ bias,
                                                 ushort_t* __restrict__ C,
                                                 int N, int K) {
  __shared__ ushort_t Alds[128 * 32];
  __shared__ ushort_t Blds[128 * 32];
  const int tid = threadIdx.x;
  const int lane = tid & 63, wave = tid >> 6;
  const int l16 = lane & 15, quad = lane >> 4;
  const int m0 = (wave >> 1) * 64, n0 = (wave & 1) * 64;
  // swizzle: gridDim.y (M-blocks, 64) divisible by 8
  const int nb = gridDim.x;
  const int flat = blockIdx.y * nb + blockIdx.x;
  const int grp = flat / (8 * nb);
  const int rem = flat - grp * 8 * nb;
  const int bm = (grp * 8 + (rem & 7)) * 128;
  const int bn = (rem >> 3) * 128;
  const int r0 = tid >> 2, koff = (tid & 3) * 8;

  const ushort_t* ga0 = A  + (size_t)(bm + r0) * K + koff;
  const ushort_t* ga1 = ga0 + (size_t)64 * K;
  const ushort_t* gb0 = Bt + (size_t)(bn + r0) * K + koff;
  const ushort_t* gb1 = gb0 + (size_t)64 * K;
  ushort_t* la0 = &Alds[tid * 8];
  ushort_t* la1 = &Alds[64 * 32 + tid * 8];
  ushort_t* lb0 = &Blds[tid * 8];
  ushort_t* lb1 = &Blds[64 * 32 + tid * 8];

  floatx4 acc[4][4] = {};
  for (int k0 = 0; k0 < K; k0 += 32) {
    __syncthreads();
    __builtin_amdgcn_global_load_lds(GLB_AS(ga0 + k0), LDS_AS(la0), 16, 0, 0);
    __builtin_amdgcn_global_load_lds(GLB_AS(ga1 + k0), LDS_AS(la1), 16, 0, 0);
    __builtin_amdgcn_global_load_lds(GLB_AS(gb0 + k0), LDS_AS(lb0), 16, 0, 0);
    __builtin_amdgcn_global_load_lds(GLB_AS(gb1 + k0), LDS_AS(lb1), 16, 0, 0);
    __syncthreads();
    short8 af[4], bf[4];
    #pragma unroll
    for (int fi = 0; fi < 4; ++fi)
      af[fi] = *(const short8*)&Alds[(m0 + fi * 16 + l16) * 32 + quad * 8];
    #pragma unroll
    for (int fj = 0; fj < 4; ++fj)
      bf[fj] = *(const short8*)&Blds[(n0 + fj * 16 + l16) * 32 + quad * 8];
    #pragma unroll
    for (int fi = 0; fi < 4; ++fi)
      #pragma unroll
      for (int fj = 0; fj < 4; ++fj)
        acc[fi][fj] = __builtin_amdgcn_mfma_f32_16x16x32_bf16(af[fi], bf[fj], acc[fi][fj], 0, 0, 0);
  }
  #pragma unroll
  for (int fi = 0; fi < 4; ++fi) {
    #pragma unroll
    for (int fj = 0; fj < 4; ++fj) {
      const int row = bm + m0 + fi * 16 + quad * 4;
      const int col = bn + n0 + fj * 16 + l16;
      const float bv = bias[col];
      #pragma unroll
      for (int r = 0; r < 4; ++r) {
        float v = acc[fi][fj][r] + bv;
        if (RELU) v = fmaxf(v, 0.0f);
        C[(size_t)(row + r) * N + col] = f2b(v);
      }
    }
  }
}

// ---------------------------------------------------------------------------
// MFMA flash attention over packed qkv (row stride 2304; q +0, k +768).
// ---------------------------------------------------------------------------
__global__ __launch_bounds__(256) void attn_mfma(const ushort_t* __restrict__ qkv,
                                                 const ushort_t* __restrict__ vT,
                                                 const ushort_t* __restrict__ bias,
                                                 ushort_t* __restrict__ o) {
  __shared__ ushort_t Qs[64][72];
  __shared__ ushort_t Ks[64][72];
  __shared__ ushort_t Vt[64][72];
  __shared__ ushort_t Ps[64][72];
  const int qt = blockIdx.x, hh = blockIdx.y, b = blockIdx.z;
  const int tid = threadIdx.x;
  const int lane = tid & 63, w = tid >> 6;
  const int l16 = lane & 15, quad = lane >> 4;

  for (int c = tid; c < 1024; c += 256) {
    const int row = c >> 4, e0 = (c & 15) * 4;
    *(ushort4*)&Qs[row][e0] =
        *(const ushort4*)(qkv + ((size_t)(b * S_ + qt * 64 + row)) * QKVN + hh * 64 + e0);
  }

  floatx4 Oa[4] = {};
  float mrow[4] = {-3e38f, -3e38f, -3e38f, -3e38f};
  float lrow[4] = {};
  const ushort_t* vbase = vT + ((size_t)(b * H_ + hh) * 64) * S_;

  for (int kt = 0; kt < 8; ++kt) {
    __syncthreads();
    for (int c = tid; c < 1024; c += 256) {
      const int row = c >> 4, e0 = (c & 15) * 4;
      *(ushort4*)&Ks[row][e0] =
          *(const ushort4*)(qkv + ((size_t)(b * S_ + kt * 64 + row)) * QKVN + 768 + hh * 64 + e0);
      *(ushort4*)&Vt[row][e0] =
          *(const ushort4*)(vbase + (size_t)row * S_ + kt * 64 + e0);
    }
    __syncthreads();

    floatx4 sa[4] = {};
    #pragma unroll
    for (int st = 0; st < 2; ++st) {
      short8 aq = *(const short8*)&Qs[w * 16 + l16][st * 32 + quad * 8];
      #pragma unroll
      for (int fj = 0; fj < 4; ++fj) {
        short8 bk = *(const short8*)&Ks[fj * 16 + l16][st * 32 + quad * 8];
        sa[fj] = __builtin_amdgcn_mfma_f32_16x16x32_bf16(aq, bk, sa[fj], 0, 0, 0);
      }
    }

    #pragma unroll
    for (int r = 0; r < 4; ++r) {
      const int qrow = qt * 64 + w * 16 + quad * 4 + r;
      const ushort_t* bp = bias + ((size_t)b * S_ + qrow) * S_ + kt * 64 + l16;
      float s0 = sa[0][r] * 0.125f + b2f(bp[0]);
      float s1 = sa[1][r] * 0.125f + b2f(bp[16]);
      float s2 = sa[2][r] * 0.125f + b2f(bp[32]);
      float s3 = sa[3][r] * 0.125f + b2f(bp[48]);
      float mt = fmaxf(fmaxf(s0, s1), fmaxf(s2, s3));
      mt = fmaxf(mt, __shfl_xor(mt, 1)); mt = fmaxf(mt, __shfl_xor(mt, 2));
      mt = fmaxf(mt, __shfl_xor(mt, 4)); mt = fmaxf(mt, __shfl_xor(mt, 8));
      const float mn = fmaxf(mrow[r], mt);
      const float alpha = __expf(mrow[r] - mn);
      mrow[r] = mn;
      float p0 = __expf(s0 - mn), p1 = __expf(s1 - mn);
      float p2 = __expf(s2 - mn), p3 = __expf(s3 - mn);
      const int prow = w * 16 + quad * 4 + r;
      Ps[prow][ 0 + l16] = f2b(p0);
      Ps[prow][16 + l16] = f2b(p1);
      Ps[prow][32 + l16] = f2b(p2);
      Ps[prow][48 + l16] = f2b(p3);
      float rs = p0 + p1 + p2 + p3;
      rs += __shfl_xor(rs, 1); rs += __shfl_xor(rs, 2);
      rs += __shfl_xor(rs, 4); rs += __shfl_xor(rs, 8);
      lrow[r] = lrow[r] * alpha + rs;
      Oa[0][r] *= alpha; Oa[1][r] *= alpha; Oa[2][r] *= alpha; Oa[3][r] *= alpha;
    }

    #pragma unroll
    for (int st = 0; st < 2; ++st) {
      short8 ap = *(const short8*)&Ps[w * 16 + l16][st * 32 + quad * 8];
      #pragma unroll
      for (int fe = 0; fe < 4; ++fe) {
        short8 bv = *(const short8*)&Vt[fe * 16 + l16][st * 32 + quad * 8];
        Oa[fe] = __builtin_amdgcn_mfma_f32_16x16x32_bf16(ap, bv, Oa[fe], 0, 0, 0);
      }
    }
  }

  #pragma unroll
  for (int r = 0; r < 4; ++r) {
    const float inv = 1.0f / lrow[r];
    const size_t tok = (size_t)(b * S_ + qt * 64 + w * 16 + quad * 4 + r);
    #pragma unroll
    for (int fe = 0; fe < 4; ++fe)
      o[tok * D_ + hh * 64 + fe * 16 + l16] = f2b(Oa[fe][r] * inv);
  }
}

// ---------------------------------------------------------------------------
__global__ __launch_bounds__(256) void add_ln(float* __restrict__ h,
                                              const ushort_t* __restrict__ r,
                                              const float* __restrict__ g,
                                              const float* __restrict__ be,
                                              ushort_t* __restrict__ h16) {
  const int t = blockIdx.x;
  const int tid = threadIdx.x;
  __shared__ float red[8];
  const size_t base = (size_t)t * D_;
  float x0 = h[base + tid]       + b2f(r[base + tid]);
  float x1 = h[base + tid + 256] + b2f(r[base + tid + 256]);
  float x2 = h[base + tid + 512] + b2f(r[base + tid + 512]);
  float s = x0 + x1 + x2;
  #pragma unroll
  for (int off = 32; off > 0; off >>= 1) s += __shfl_down(s, off);
  if ((tid & 63) == 0) red[tid >> 6] = s;
  __syncthreads();
  if (tid == 0) red[4] = (red[0] + red[1] + red[2] + red[3]) * (1.0f / 768.0f);
  __syncthreads();
  const float m = red[4];
  float d0 = x0 - m, d1 = x1 - m, d2 = x2 - m;
  float s2 = d0 * d0 + d1 * d1 + d2 * d2;
  #pragma unroll
  for (int off = 32; off > 0; off >>= 1) s2 += __shfl_down(s2, off);
  if ((tid & 63) == 0) red[tid >> 6] = s2;
  __syncthreads();
  if (tid == 0) red[5] = (red[0] + red[1] + red[2] + red[3]) * (1.0f / 768.0f);
  __syncthreads();
  const float rs = rsqrtf(red[5] + 1e-5f);
  float y0 = d0 * rs * g[tid]       + be[tid];
  float y1 = d1 * rs * g[tid + 256] + be[tid + 256];
  float y2 = d2 * rs * g[tid + 512] + be[tid + 512];
  h[base + tid]       = y0; h16[base + tid]       = f2b(y0);
  h[base + tid + 256] = y1; h16[base + tid + 256] = f2b(y1);
  h[base + tid + 512] = y2; h16[base + tid + 512] = f2b(y2);
}

__global__ __launch_bounds__(256) void write_out(const float* __restrict__ h,
                                                 float* __restrict__ out, int n) {
  int i = blockIdx.x * 256 + threadIdx.x;
  if (i < n) out[i] = h[i];
}

// ---------------------------------------------------------------------------
extern "C" void kernel_launch(void* const* d_in, const int* in_sizes, int n_in,
                              void* d_out, int out_size, void* d_ws, size_t ws_size,
                              hipStream_t stream) {
  (void)in_sizes; (void)n_in; (void)out_size; (void)ws_size;
  const int* x    = (const int*)d_in[0];
  const int* mask = (const int*)d_in[1];
  const float* emb = (const float*)d_in[2];
  const float* Wq  = (const float*)d_in[3];
  const float* bq  = (const float*)d_in[4];
  const float* Wk  = (const float*)d_in[5];
  const float* bk  = (const float*)d_in[6];
  const float* Wv  = (const float*)d_in[7];
  const float* bv  = (const float*)d_in[8];
  const float* Wo  = (const float*)d_in[9];
  const float* bo  = (const float*)d_in[10];
  const float* W1  = (const float*)d_in[11];
  const float* b1  = (const float*)d_in[12];
  const float* W2  = (const float*)d_in[13];
  const float* b2  = (const float*)d_in[14];
  const float* g1  = (const float*)d_in[15];
  const float* be1 = (const float*)d_in[16];
  const float* g2  = (const float*)d_in[17];
  const float* be2 = (const float*)d_in[18];

  const size_t TD  = (size_t)T_ * D_;            // 6,291,456
  const size_t DD  = (size_t)D_ * D_;            // 589,824
  const size_t WDD = (size_t)L_ * DD;
  const size_t WDF = (size_t)L_ * D_ * F_;

  float* h32 = (float*)d_ws;                     // 24 MB
  ushort_t* h16  = (ushort_t*)(h32 + TD);
  ushort_t* qkv16 = h16 + TD;                    // [T][2304] = 3*TD
  ushort_t* o1   = qkv16 + 3 * TD;
  ushort_t* o2   = o1 + TD;
  ushort_t* ff   = qkv16;                        // [T][3072] aliases qkv|o1
  ushort_t* vT   = o2 + TD;                      // [B*H][64][512]
  ushort_t* bias16 = vT + TD;                    // [B][S][S]
  ushort_t* WqkvT = bias16 + (size_t)B_ * S_ * S_;  // [L][2304][768]
  ushort_t* WoT  = WqkvT + 3 * WDD;
  ushort_t* W1T  = WoT + WDD;
  ushort_t* W2T  = W1T + WDF;
  float* bqkv    = (float*)(W2T + WDF);          // [L][2304]
  int* xstride   = (int*)(bqkv + (size_t)L_ * QKVN);

  probe_x<<<dim3(1), 64, 0, stream>>>(x, xstride);
  // Wq/Wk/Wv [L,H,768,64] -> WqkvT [L][2304][768]; q rows 0-767,k 768-,v 1536-
  transpose_cast<<<dim3(2, 24, 72), 256, 0, stream>>>(Wq, WqkvT,          768, 64, 12, 3 * DD, (size_t)64 * 768);
  transpose_cast<<<dim3(2, 24, 72), 256, 0, stream>>>(Wk, WqkvT + DD,     768, 64, 12, 3 * DD, (size_t)64 * 768);
  transpose_cast<<<dim3(2, 24, 72), 256, 0, stream>>>(Wv, WqkvT + 2 * DD, 768, 64, 12, 3 * DD, (size_t)64 * 768);
  transpose_cast<<<dim3(24, 24, 6), 256, 0, stream>>>(Wo, WoT, 768, 768, 1, DD, 0);
  transpose_cast<<<dim3(96, 24, 6), 256, 0, stream>>>(W1, W1T, 768, 3072, 1, (size_t)D_ * F_, 0);
  transpose_cast<<<dim3(24, 96, 6), 256, 0, stream>>>(W2, W2T, 3072, 768, 1, (size_t)D_ * F_, 0);
  pack_bias<<<dim3((L_ * D_ + 255) / 256), 256, 0, stream>>>(bq, bk, bv, bqkv);
  mask_bias<<<dim3((B_ * S_ * S_) / 1024), 256, 0, stream>>>(mask, bias16);
  embed_pe<<<dim3(T_), 256, 0, stream>>>(x, xstride, emb, h32, h16);

  const dim3 gQKV(QKVN / 128, T_ / 128);  // 18 x 64
  const dim3 gD(D_ / 128, T_ / 128);      // 6 x 64
  const dim3 gF(F_ / 128, T_ / 128);      // 24 x 64
  for (int l = 0; l < L_; ++l) {
    const size_t oDD = (size_t)l * DD;
    const size_t oDF = (size_t)l * D_ * F_;
    gemm_mfma<0><<<gQKV, 256, 0, stream>>>(h16, WqkvT + (size_t)l * 3 * DD, bqkv + (size_t)l * QKVN, qkv16, QKVN, D_);
    transpose_v<<<dim3(16, 2, B_ * H_), 256, 0, stream>>>(qkv16, vT);
    attn_mfma<<<dim3(8, H_, B_), 256, 0, stream>>>(qkv16, vT, bias16, o1);
    gemm_mfma<0><<<gD, 256, 0, stream>>>(o1, WoT + oDD, bo + l * D_, o2, D_, D_);
    add_ln<<<dim3(T_), 256, 0, stream>>>(h32, o2, g1 + l * D_, be1 + l * D_, h16);
    gemm_mfma<1><<<gF, 256, 0, stream>>>(h16, W1T + oDF, b1 + l * F_, ff, F_, D_);
    gemm_mfma<0><<<gD, 256, 0, stream>>>(ff, W2T + oDF, b2 + l * D_, o2, D_, F_);
    add_ln<<<dim3(T_), 256, 0, stream>>>(h32, o2, g2 + l * D_, be2 + l * D_, h16);
  }
  write_out<<<dim3((unsigned)(TD / 256)), 256, 0, stream>>>(h32, (float*)d_out, (int)TD);
}